// Round 1
// baseline (309.137 us; speedup 1.0000x reference)
//
#include <hip/hip_runtime.h>
#include <math.h>

#define HWSZ 1024
#define HH 32
#define WW 32
#define C 256
#define CK 32
#define CV 128
#define T 3
#define WSZ 15
#define PADSZ 7
#define PADDED 46
#define PP (PADDED*PADDED)   // 2116
#define KK (T*WSZ*WSZ)       // 675
#define B 2

// workspace layout (floats)
static const size_t OFF_QK   = 0;                          // B*HWSZ*CK   = 65536
static const size_t OFF_QV   = 65536;                      // B*HWSZ*CV   = 262144
static const size_t OFF_MK   = 65536 + 262144;             // B*T*CK*PP   = 406272 (channel-first padded)
static const size_t OFF_MV   = 327680 + 406272;            // B*T*PP*CV   = 1625088 (channel-last padded)
static const size_t OFF_ATTN = 733952 + 1625088;           // B*HWSZ*KK   = 1382400
static const size_t OFF_MO   = 2359040 + 1382400;          // B*HWSZ*CV   = 262144
static const size_t ZERO_N   = 406272 + 1625088;           // mk+mv pad regions

__global__ __launch_bounds__(256) void k_zero(float* __restrict__ p, int n) {
    int i = blockIdx.x * 256 + threadIdx.x;
    if (i < n) p[i] = 0.f;
}

// One block per (b,t,h,w) pixel. Stage 256-ch input in LDS, each thread one output dot.
__global__ __launch_bounds__(256) void k_proj(
    const float* __restrict__ x, const float* __restrict__ mem,
    const float* __restrict__ w_qk, const float* __restrict__ w_qv,
    const float* __restrict__ w_mk, const float* __restrict__ w_mv,
    float* __restrict__ ws)
{
    __shared__ float in[C];
    int pix = blockIdx.x;
    int wq = pix & 31;
    int hq = (pix >> 5) & 31;
    int t  = (pix >> 10) % T;
    int b  = pix / (HWSZ * T);
    int hw = hq * WW + wq;

    const float* src = (t == 0)
        ? (x + ((size_t)b * C) * HWSZ + hw)
        : (mem + ((size_t)(b * (T - 1) + (t - 1)) * C) * HWSZ + hw);
    in[threadIdx.x] = src[(size_t)threadIdx.x * HWSZ];
    __syncthreads();

    int tid = threadIdx.x;
    int yp = hq + PADSZ, xp = wq + PADSZ;
    float* mk = ws + OFF_MK;
    float* mv = ws + OFF_MV;

    if (tid < CK) {
        const float* wr = w_mk + (size_t)tid * C;
        float acc = 0.f;
        #pragma unroll 8
        for (int c = 0; c < C; c++) acc += wr[c] * in[c];
        mk[(((size_t)(b * T + t) * CK + tid) * PP) + yp * PADDED + xp] = acc;
    } else if (tid < CK + CV) {
        int o = tid - CK;
        const float* wr = w_mv + (size_t)o * C;
        float acc = 0.f;
        #pragma unroll 8
        for (int c = 0; c < C; c++) acc += wr[c] * in[c];
        mv[((size_t)(b * T + t) * PP + yp * PADDED + xp) * CV + o] = acc;
    }
    if (t == 0) {
        if (tid < CK) {
            const float* wr = w_qk + (size_t)tid * C;
            float acc = 0.f;
            #pragma unroll 8
            for (int c = 0; c < C; c++) acc += wr[c] * in[c];
            ws[OFF_QK + ((size_t)b * HWSZ + hw) * CK + tid] = acc;
        } else if (tid < CK + CV) {
            int o = tid - CK;
            const float* wr = w_qv + (size_t)o * C;
            float acc = 0.f;
            #pragma unroll 8
            for (int c = 0; c < C; c++) acc += wr[c] * in[c];
            ws[OFF_QV + ((size_t)b * HWSZ + hw) * CV + o] = acc;
        }
    }
}

// One block per (b,h,w) pixel; threads over k=(t,x,y).
__global__ __launch_bounds__(256) void k_attn(
    const float* __restrict__ qk, const float* __restrict__ mk,
    float* __restrict__ attn)
{
    __shared__ float q[CK];
    int pix = blockIdx.x;                 // b*HWSZ + hw
    int wq = pix & 31, hq = (pix >> 5) & 31, b = pix >> 10;
    if (threadIdx.x < CK) q[threadIdx.x] = qk[(size_t)pix * CK + threadIdx.x];
    __syncthreads();

    float* arow = attn + (size_t)pix * KK;
    for (int k = threadIdx.x; k < KK; k += 256) {
        int t = k / (WSZ * WSZ);
        int r = k % (WSZ * WSZ);
        int xx = r / WSZ, yy = r % WSZ;
        const float* base = mk + ((size_t)(b * T + t) * CK) * PP
                               + (size_t)(hq + xx) * PADDED + (wq + yy);
        float acc = 0.f;
        #pragma unroll
        for (int c = 0; c < CK; c++) acc += q[c] * base[(size_t)c * PP];
        arow[k] = acc;
    }
}

// Softmax over the w axis (axis=2 of (b,h,w,K)) — one thread per (b,h,k).
__global__ __launch_bounds__(256) void k_softmax(float* __restrict__ attn)
{
    int idx = blockIdx.x * 256 + threadIdx.x;
    if (idx >= B * HH * KK) return;
    int k = idx % KK;
    int bh = idx / KK;                    // b*HH + h
    float* p = attn + ((size_t)bh * WW) * KK + k;
    float v[WW];
    float m = -1e30f;
    #pragma unroll
    for (int i = 0; i < WW; i++) { v[i] = p[(size_t)i * KK]; m = fmaxf(m, v[i]); }
    float s = 0.f;
    #pragma unroll
    for (int i = 0; i < WW; i++) { v[i] = __expf(v[i] - m); s += v[i]; }
    float inv = 1.0f / s;
    #pragma unroll
    for (int i = 0; i < WW; i++) p[(size_t)i * KK] = v[i] * inv;
}

// One block per pixel, attn row in LDS (broadcast), thread per v-channel (coalesced mv reads).
__global__ __launch_bounds__(128) void k_av(
    const float* __restrict__ attn, const float* __restrict__ mv,
    float* __restrict__ mo)
{
    __shared__ float a[KK];
    int pix = blockIdx.x;
    int wq = pix & 31, hq = (pix >> 5) & 31, b = pix >> 10;
    for (int k = threadIdx.x; k < KK; k += 128) a[k] = attn[(size_t)pix * KK + k];
    __syncthreads();

    int c = threadIdx.x;
    float acc = 0.f;
    int ak = 0;
    for (int t = 0; t < T; t++) {
        for (int xx = 0; xx < WSZ; xx++) {
            const float* row = mv + ((size_t)(b * T + t) * PP
                                     + (size_t)(hq + xx) * PADDED + wq) * CV + c;
            #pragma unroll
            for (int yy = 0; yy < WSZ; yy++) acc += a[ak++] * row[(size_t)yy * CV];
        }
    }
    mo[(size_t)pix * CV + c] = acc;
}

// feat = [qv; mo] -> w_smooth matmul -> BN(eval) -> ReLU. Block per pixel, thread per out channel.
__global__ __launch_bounds__(256) void k_out(
    const float* __restrict__ qv, const float* __restrict__ mo,
    const float* __restrict__ wsm,
    const float* __restrict__ g, const float* __restrict__ bta,
    const float* __restrict__ mean, const float* __restrict__ var,
    float* __restrict__ out)
{
    __shared__ float f[C];
    int pix = blockIdx.x;
    int b = pix >> 10, hw = pix & 1023;
    int tid = threadIdx.x;
    f[tid] = (tid < CV) ? qv[(size_t)pix * CV + tid]
                        : mo[(size_t)pix * CV + (tid - CV)];
    __syncthreads();

    const float* wr = wsm + (size_t)tid * C;
    float acc = 0.f;
    #pragma unroll 8
    for (int c = 0; c < C; c++) acc += wr[c] * f[c];
    float inv = g[tid] * rsqrtf(var[tid] + 1e-5f);
    float yv = acc * inv + (bta[tid] - mean[tid] * inv);
    out[((size_t)(b * C + tid)) * HWSZ + hw] = fmaxf(yv, 0.f);
}

extern "C" void kernel_launch(void* const* d_in, const int* in_sizes, int n_in,
                              void* d_out, int out_size, void* d_ws, size_t ws_size,
                              hipStream_t stream) {
    const float* x    = (const float*)d_in[0];
    const float* mem  = (const float*)d_in[1];
    const float* w_qk = (const float*)d_in[2];
    const float* w_qv = (const float*)d_in[3];
    const float* w_mk = (const float*)d_in[4];
    const float* w_mv = (const float*)d_in[5];
    const float* wsm  = (const float*)d_in[6];
    const float* g    = (const float*)d_in[7];
    const float* bta  = (const float*)d_in[8];
    const float* mean = (const float*)d_in[9];
    const float* var  = (const float*)d_in[10];
    float* out = (float*)d_out;
    float* ws  = (float*)d_ws;

    // zero padded mk/mv regions
    {
        int n = (int)ZERO_N;
        k_zero<<<(n + 255) / 256, 256, 0, stream>>>(ws + OFF_MK, n);
    }
    k_proj<<<B * T * HWSZ, 256, 0, stream>>>(x, mem, w_qk, w_qv, w_mk, w_mv, ws);
    k_attn<<<B * HWSZ, 256, 0, stream>>>(ws + OFF_QK, ws + OFF_MK, ws + OFF_ATTN);
    {
        int n = B * HH * KK;
        k_softmax<<<(n + 255) / 256, 256, 0, stream>>>(ws + OFF_ATTN);
    }
    k_av<<<B * HWSZ, 128, 0, stream>>>(ws + OFF_ATTN, ws + OFF_MV, ws + OFF_MO);
    k_out<<<B * HWSZ, 256, 0, stream>>>(ws + OFF_QV, ws + OFF_MO, wsm, g, bta, mean, var, out);
}

// Round 2
// 156.664 us; speedup vs baseline: 1.9732x; 1.9732x over previous
//
#include <hip/hip_runtime.h>
#include <math.h>

#define HWSZ 1024
#define HH 32
#define WW 32
#define C 256
#define CK 32
#define CV 128
#define T 3
#define WSZ 15
#define PADSZ 7
#define PADDED 46
#define PP (PADDED*PADDED)   // 2116
#define KK (T*WSZ*WSZ)       // 675
#define B 2
#define NOUT 160             // CK + CV
#define KC 32                // k-chunk
#define PIXT 32              // pixel tile (one image row)

// workspace layout (floats)
static const size_t OFF_QK   = 0;                          // B*HWSZ*CK   = 65536
static const size_t OFF_QV   = 65536;                      // B*HWSZ*CV   = 262144
static const size_t OFF_MK   = 65536 + 262144;             // B*T*CK*PP   = 406272 (channel-first padded)
static const size_t OFF_MV   = 327680 + 406272;            // B*T*PP*CV   = 1625088 (channel-last padded)
static const size_t OFF_ATTN = 733952 + 1625088;           // B*HWSZ*KK   = 1382400
static const size_t OFF_MO   = 2359040 + 1382400;          // B*HWSZ*CV   = 262144
static const size_t ZERO_N   = 406272 + 1625088;           // mk+mv pad regions

__global__ __launch_bounds__(256) void k_zero(float* __restrict__ p, int n) {
    int i = blockIdx.x * 256 + threadIdx.x;
    if (i < n) p[i] = 0.f;
}

// Tiled GEMM proj. Grid = 8 jobs * 32 row-tiles.
// jobs 0..5: (b,t) mem proj -> mk (ch-first padded), mv (ch-last padded)
// jobs 6..7: b q proj       -> qk [pix][32], qv [pix][128]
__global__ __launch_bounds__(256) void k_proj(
    const float* __restrict__ x, const float* __restrict__ mem,
    const float* __restrict__ w_qk, const float* __restrict__ w_qv,
    const float* __restrict__ w_mk, const float* __restrict__ w_mv,
    float* __restrict__ ws)
{
    __shared__ float inT[KC][PIXT];      // 4 KB
    __shared__ float wT[NOUT][KC + 1];   // ~21 KB (pad kills bank conflicts)

    int jb   = blockIdx.x >> 5;          // 0..7
    int rowt = blockIdx.x & 31;          // h row
    int tid  = threadIdx.x;
    int tx   = tid & 7;                  // pixel quad
    int ty   = tid >> 3;                 // 5 outputs

    int b, t;
    const float *wk, *wv;
    bool isq;
    if (jb < 6) { b = jb / 3; t = jb % 3; wk = w_mk; wv = w_mv; isq = false; }
    else        { b = jb - 6; t = 0;      wk = w_qk; wv = w_qv; isq = true;  }

    const float* src = (t == 0)
        ? (x + ((size_t)b * C) * HWSZ)
        : (mem + ((size_t)(b * (T - 1) + (t - 1)) * C) * HWSZ);
    int hw0 = rowt * WW;

    float acc[5][4];
    #pragma unroll
    for (int j = 0; j < 5; j++)
        #pragma unroll
        for (int i = 0; i < 4; i++) acc[j][i] = 0.f;

    for (int c0 = 0; c0 < C; c0 += KC) {
        // stage input tile: 32 ch x 32 px, coalesced float4
        {
            int cc = tid >> 3;           // 0..31
            int p4 = (tid & 7) * 4;
            float4 v = *(const float4*)&src[(size_t)(c0 + cc) * HWSZ + hw0 + p4];
            inT[cc][p4 + 0] = v.x; inT[cc][p4 + 1] = v.y;
            inT[cc][p4 + 2] = v.z; inT[cc][p4 + 3] = v.w;
        }
        // stage weight tile: 160 o x 32 c (rows 0..31 from wk, 32..159 from wv)
        #pragma unroll
        for (int j = 0; j < 5; j++) {
            int f  = tid + j * 256;      // float4 index, 0..1279
            int o  = f >> 3;
            int c4 = (f & 7) * 4;
            const float* wr = (o < CK) ? (wk + (size_t)o * C) : (wv + (size_t)(o - CK) * C);
            float4 v = *(const float4*)&wr[c0 + c4];
            wT[o][c4 + 0] = v.x; wT[o][c4 + 1] = v.y;
            wT[o][c4 + 2] = v.z; wT[o][c4 + 3] = v.w;
        }
        __syncthreads();

        #pragma unroll 8
        for (int k = 0; k < KC; k++) {
            float4 iv = *(const float4*)&inT[k][tx * 4];
            #pragma unroll
            for (int j = 0; j < 5; j++) {
                float wv_ = wT[ty * 5 + j][k];
                acc[j][0] += wv_ * iv.x; acc[j][1] += wv_ * iv.y;
                acc[j][2] += wv_ * iv.z; acc[j][3] += wv_ * iv.w;
            }
        }
        __syncthreads();
    }

    // write out
    int hq = rowt, yp = hq + PADSZ;
    float* mk = ws + OFF_MK;
    float* mv = ws + OFF_MV;
    #pragma unroll
    for (int j = 0; j < 5; j++) {
        int o = ty * 5 + j;
        #pragma unroll
        for (int i = 0; i < 4; i++) {
            int wq = tx * 4 + i;
            float v = acc[j][i];
            if (!isq) {
                int xp = wq + PADSZ;
                if (o < CK)
                    mk[(((size_t)(b * T + t) * CK + o) * PP) + yp * PADDED + xp] = v;
                else
                    mv[((size_t)(b * T + t) * PP + yp * PADDED + xp) * CV + (o - CK)] = v;
            } else {
                size_t pixi = (size_t)b * HWSZ + hq * WW + wq;
                if (o < CK) ws[OFF_QK + pixi * CK + o] = v;
                else        ws[OFF_QV + pixi * CV + (o - CK)] = v;
            }
        }
    }
}

// One block per (b,h,w) pixel; threads over k=(t,x,y).
__global__ __launch_bounds__(256) void k_attn(
    const float* __restrict__ qk, const float* __restrict__ mk,
    float* __restrict__ attn)
{
    __shared__ float q[CK];
    int pix = blockIdx.x;                 // b*HWSZ + hw
    int wq = pix & 31, hq = (pix >> 5) & 31, b = pix >> 10;
    if (threadIdx.x < CK) q[threadIdx.x] = qk[(size_t)pix * CK + threadIdx.x];
    __syncthreads();

    float* arow = attn + (size_t)pix * KK;
    for (int k = threadIdx.x; k < KK; k += 256) {
        int t = k / (WSZ * WSZ);
        int r = k % (WSZ * WSZ);
        int xx = r / WSZ, yy = r % WSZ;
        const float* base = mk + ((size_t)(b * T + t) * CK) * PP
                               + (size_t)(hq + xx) * PADDED + (wq + yy);
        float acc = 0.f;
        #pragma unroll
        for (int c = 0; c < CK; c++) acc += q[c] * base[(size_t)c * PP];
        arow[k] = acc;
    }
}

// Softmax over the w axis (axis=2 of (b,h,w,K)) — one thread per (b,h,k).
__global__ __launch_bounds__(256) void k_softmax(float* __restrict__ attn)
{
    int idx = blockIdx.x * 256 + threadIdx.x;
    if (idx >= B * HH * KK) return;
    int k = idx % KK;
    int bh = idx / KK;                    // b*HH + h
    float* p = attn + ((size_t)bh * WW) * KK + k;
    float v[WW];
    float m = -1e30f;
    #pragma unroll
    for (int i = 0; i < WW; i++) { v[i] = p[(size_t)i * KK]; m = fmaxf(m, v[i]); }
    float s = 0.f;
    #pragma unroll
    for (int i = 0; i < WW; i++) { v[i] = __expf(v[i] - m); s += v[i]; }
    float inv = 1.0f / s;
    #pragma unroll
    for (int i = 0; i < WW; i++) p[(size_t)i * KK] = v[i] * inv;
}

// One block per pixel, attn row in LDS (broadcast), thread per v-channel (coalesced mv reads).
__global__ __launch_bounds__(128) void k_av(
    const float* __restrict__ attn, const float* __restrict__ mv,
    float* __restrict__ mo)
{
    __shared__ float a[KK];
    int pix = blockIdx.x;
    int wq = pix & 31, hq = (pix >> 5) & 31, b = pix >> 10;
    for (int k = threadIdx.x; k < KK; k += 128) a[k] = attn[(size_t)pix * KK + k];
    __syncthreads();

    int c = threadIdx.x;
    float acc = 0.f;
    int ak = 0;
    for (int t = 0; t < T; t++) {
        for (int xx = 0; xx < WSZ; xx++) {
            const float* row = mv + ((size_t)(b * T + t) * PP
                                     + (size_t)(hq + xx) * PADDED + wq) * CV + c;
            #pragma unroll
            for (int yy = 0; yy < WSZ; yy++) acc += a[ak++] * row[(size_t)yy * CV];
        }
    }
    mo[(size_t)pix * CV + c] = acc;
}

// feat = [qv; mo] -> w_smooth matmul -> BN(eval) -> ReLU. Block per pixel, thread per out channel.
__global__ __launch_bounds__(256) void k_out(
    const float* __restrict__ qv, const float* __restrict__ mo,
    const float* __restrict__ wsm,
    const float* __restrict__ g, const float* __restrict__ bta,
    const float* __restrict__ mean, const float* __restrict__ var,
    float* __restrict__ out)
{
    __shared__ float f[C];
    int pix = blockIdx.x;
    int b = pix >> 10, hw = pix & 1023;
    int tid = threadIdx.x;
    f[tid] = (tid < CV) ? qv[(size_t)pix * CV + tid]
                        : mo[(size_t)pix * CV + (tid - CV)];
    __syncthreads();

    const float* wr = wsm + (size_t)tid * C;
    float acc = 0.f;
    #pragma unroll 8
    for (int c = 0; c < C; c++) acc += wr[c] * f[c];
    float inv = g[tid] * rsqrtf(var[tid] + 1e-5f);
    float yv = acc * inv + (bta[tid] - mean[tid] * inv);
    out[((size_t)(b * C + tid)) * HWSZ + hw] = fmaxf(yv, 0.f);
}

extern "C" void kernel_launch(void* const* d_in, const int* in_sizes, int n_in,
                              void* d_out, int out_size, void* d_ws, size_t ws_size,
                              hipStream_t stream) {
    const float* x    = (const float*)d_in[0];
    const float* mem  = (const float*)d_in[1];
    const float* w_qk = (const float*)d_in[2];
    const float* w_qv = (const float*)d_in[3];
    const float* w_mk = (const float*)d_in[4];
    const float* w_mv = (const float*)d_in[5];
    const float* wsm  = (const float*)d_in[6];
    const float* g    = (const float*)d_in[7];
    const float* bta  = (const float*)d_in[8];
    const float* mean = (const float*)d_in[9];
    const float* var  = (const float*)d_in[10];
    float* out = (float*)d_out;
    float* ws  = (float*)d_ws;

    // zero padded mk/mv regions
    {
        int n = (int)ZERO_N;
        k_zero<<<(n + 255) / 256, 256, 0, stream>>>(ws + OFF_MK, n);
    }
    k_proj<<<8 * 32, 256, 0, stream>>>(x, mem, w_qk, w_qv, w_mk, w_mv, ws);
    k_attn<<<B * HWSZ, 256, 0, stream>>>(ws + OFF_QK, ws + OFF_MK, ws + OFF_ATTN);
    {
        int n = B * HH * KK;
        k_softmax<<<(n + 255) / 256, 256, 0, stream>>>(ws + OFF_ATTN);
    }
    k_av<<<B * HWSZ, 128, 0, stream>>>(ws + OFF_ATTN, ws + OFF_MV, ws + OFF_MO);
    k_out<<<B * HWSZ, 256, 0, stream>>>(ws + OFF_QV, ws + OFF_MO, wsm, g, bta, mean, var, out);
}

// Round 3
// 112.825 us; speedup vs baseline: 2.7400x; 1.3886x over previous
//
#include <hip/hip_runtime.h>
#include <math.h>

#define HWSZ 1024
#define HH 32
#define WW 32
#define C 256
#define CK 32
#define CV 128
#define T 3
#define WSZ 15
#define PADSZ 7
#define PADDED 46
#define PP (PADDED*PADDED)   // 2116
#define KK (T*WSZ*WSZ)       // 675
#define B 2
#define NOUT 160             // CK + CV
#define KC 32                // k-chunk
#define PIXT 32              // pixel tile (one image row)

// workspace layout (floats)
static const size_t OFF_QK   = 0;                          // B*HWSZ*CK   = 65536
static const size_t OFF_QV   = 65536;                      // B*HWSZ*CV   = 262144
static const size_t OFF_MK   = 65536 + 262144;             // B*T*CK*PP   = 406272 (channel-first padded)
static const size_t OFF_MV   = 327680 + 406272;            // B*T*PP*CV   = 1625088 (channel-last padded)
static const size_t OFF_ATTN = 733952 + 1625088;           // B*HWSZ*KK   = 1382400
static const size_t OFF_MO   = 2359040 + 1382400;          // B*HWSZ*CV   = 262144
static const size_t ZERO_N   = 406272 + 1625088;           // mk+mv pad regions

__global__ __launch_bounds__(256) void k_zero(float* __restrict__ p, int n) {
    int i = blockIdx.x * 256 + threadIdx.x;
    if (i < n) p[i] = 0.f;
}

// Tiled GEMM proj. Grid = 8 jobs * 32 row-tiles.
__global__ __launch_bounds__(256) void k_proj(
    const float* __restrict__ x, const float* __restrict__ mem,
    const float* __restrict__ w_qk, const float* __restrict__ w_qv,
    const float* __restrict__ w_mk, const float* __restrict__ w_mv,
    float* __restrict__ ws)
{
    __shared__ float inT[KC][PIXT];      // 4 KB
    __shared__ float wT[NOUT][KC + 1];   // ~21 KB

    int jb   = blockIdx.x >> 5;          // 0..7
    int rowt = blockIdx.x & 31;          // h row
    int tid  = threadIdx.x;
    int tx   = tid & 7;                  // pixel quad
    int ty   = tid >> 3;                 // 5 outputs

    int b, t;
    const float *wk, *wv;
    bool isq;
    if (jb < 6) { b = jb / 3; t = jb % 3; wk = w_mk; wv = w_mv; isq = false; }
    else        { b = jb - 6; t = 0;      wk = w_qk; wv = w_qv; isq = true;  }

    const float* src = (t == 0)
        ? (x + ((size_t)b * C) * HWSZ)
        : (mem + ((size_t)(b * (T - 1) + (t - 1)) * C) * HWSZ);
    int hw0 = rowt * WW;

    float acc[5][4];
    #pragma unroll
    for (int j = 0; j < 5; j++)
        #pragma unroll
        for (int i = 0; i < 4; i++) acc[j][i] = 0.f;

    for (int c0 = 0; c0 < C; c0 += KC) {
        {
            int cc = tid >> 3;           // 0..31
            int p4 = (tid & 7) * 4;
            float4 v = *(const float4*)&src[(size_t)(c0 + cc) * HWSZ + hw0 + p4];
            inT[cc][p4 + 0] = v.x; inT[cc][p4 + 1] = v.y;
            inT[cc][p4 + 2] = v.z; inT[cc][p4 + 3] = v.w;
        }
        #pragma unroll
        for (int j = 0; j < 5; j++) {
            int f  = tid + j * 256;      // float4 index, 0..1279
            int o  = f >> 3;
            int c4 = (f & 7) * 4;
            const float* wr = (o < CK) ? (wk + (size_t)o * C) : (wv + (size_t)(o - CK) * C);
            float4 v = *(const float4*)&wr[c0 + c4];
            wT[o][c4 + 0] = v.x; wT[o][c4 + 1] = v.y;
            wT[o][c4 + 2] = v.z; wT[o][c4 + 3] = v.w;
        }
        __syncthreads();

        #pragma unroll 8
        for (int k = 0; k < KC; k++) {
            float4 iv = *(const float4*)&inT[k][tx * 4];
            #pragma unroll
            for (int j = 0; j < 5; j++) {
                float wv_ = wT[ty * 5 + j][k];
                acc[j][0] += wv_ * iv.x; acc[j][1] += wv_ * iv.y;
                acc[j][2] += wv_ * iv.z; acc[j][3] += wv_ * iv.w;
            }
        }
        __syncthreads();
    }

    int hq = rowt, yp = hq + PADSZ;
    float* mk = ws + OFF_MK;
    float* mv = ws + OFF_MV;
    #pragma unroll
    for (int j = 0; j < 5; j++) {
        int o = ty * 5 + j;
        #pragma unroll
        for (int i = 0; i < 4; i++) {
            int wq = tx * 4 + i;
            float v = acc[j][i];
            if (!isq) {
                int xp = wq + PADSZ;
                if (o < CK)
                    mk[(((size_t)(b * T + t) * CK + o) * PP) + yp * PADDED + xp] = v;
                else
                    mv[((size_t)(b * T + t) * PP + yp * PADDED + xp) * CV + (o - CK)] = v;
            } else {
                size_t pixi = (size_t)b * HWSZ + hq * WW + wq;
                if (o < CK) ws[OFF_QK + pixi * CK + o] = v;
                else        ws[OFF_QV + pixi * CV + (o - CK)] = v;
            }
        }
    }
}

// One block per (b,h,w) pixel; threads over k=(t,x,y).
__global__ __launch_bounds__(256) void k_attn(
    const float* __restrict__ qk, const float* __restrict__ mk,
    float* __restrict__ attn)
{
    __shared__ float q[CK];
    int pix = blockIdx.x;                 // b*HWSZ + hw
    int wq = pix & 31, hq = (pix >> 5) & 31, b = pix >> 10;
    if (threadIdx.x < CK) q[threadIdx.x] = qk[(size_t)pix * CK + threadIdx.x];
    __syncthreads();

    float* arow = attn + (size_t)pix * KK;
    for (int k = threadIdx.x; k < KK; k += 256) {
        int t = k / (WSZ * WSZ);
        int r = k % (WSZ * WSZ);
        int xx = r / WSZ, yy = r % WSZ;
        const float* base = mk + ((size_t)(b * T + t) * CK) * PP
                               + (size_t)(hq + xx) * PADDED + (wq + yy);
        float acc = 0.f;
        #pragma unroll
        for (int c = 0; c < CK; c++) acc += q[c] * base[(size_t)c * PP];
        arow[k] = acc;
    }
}

// Softmax over the w axis (axis=2 of (b,h,w,K)) — one thread per (b,h,k).
__global__ __launch_bounds__(256) void k_softmax(float* __restrict__ attn)
{
    int idx = blockIdx.x * 256 + threadIdx.x;
    if (idx >= B * HH * KK) return;
    int k = idx % KK;
    int bh = idx / KK;                    // b*HH + h
    float* p = attn + ((size_t)bh * WW) * KK + k;
    float v[WW];
    float m = -1e30f;
    #pragma unroll
    for (int i = 0; i < WW; i++) { v[i] = p[(size_t)i * KK]; m = fmaxf(m, v[i]); }
    float s = 0.f;
    #pragma unroll
    for (int i = 0; i < WW; i++) { v[i] = __expf(v[i] - m); s += v[i]; }
    float inv = 1.0f / s;
    #pragma unroll
    for (int i = 0; i < WW; i++) p[(size_t)i * KK] = v[i] * inv;
}

// One block per pixel, attn row in LDS (broadcast), thread per v-channel.
__global__ __launch_bounds__(128) void k_av(
    const float* __restrict__ attn, const float* __restrict__ mv,
    float* __restrict__ mo)
{
    __shared__ float a[KK];
    int pix = blockIdx.x;
    int wq = pix & 31, hq = (pix >> 5) & 31, b = pix >> 10;
    for (int k = threadIdx.x; k < KK; k += 128) a[k] = attn[(size_t)pix * KK + k];
    __syncthreads();

    int c = threadIdx.x;
    float acc = 0.f;
    int ak = 0;
    for (int t = 0; t < T; t++) {
        for (int xx = 0; xx < WSZ; xx++) {
            const float* row = mv + ((size_t)(b * T + t) * PP
                                     + (size_t)(hq + xx) * PADDED + wq) * CV + c;
            #pragma unroll
            for (int yy = 0; yy < WSZ; yy++) acc += a[ak++] * row[(size_t)yy * CV];
        }
    }
    mo[(size_t)pix * CV + c] = acc;
}

// Tiled GEMM out: feat=[qv;mo] @ w_smooth^T -> BN -> ReLU.
// Grid = B * 32 rowtiles * 2 output-halves. Block 256: 32 px x 128 outs.
__global__ __launch_bounds__(256) void k_out(
    const float* __restrict__ qv, const float* __restrict__ mo,
    const float* __restrict__ wsm,
    const float* __restrict__ g, const float* __restrict__ bta,
    const float* __restrict__ mean, const float* __restrict__ var,
    float* __restrict__ out)
{
    __shared__ float inT[KC][PIXT];      // 4 KB, [ch][px]
    __shared__ float wTt[KC][132];       // 16.9 KB, [ch][o], row stride 132 (16B aligned)

    int blk  = blockIdx.x;
    int oh   = blk & 1;                  // output half
    int rowt = (blk >> 1) & 31;
    int b    = blk >> 6;
    int tid  = threadIdx.x;
    int tx   = tid & 7;                  // pixel quad
    int ty   = tid >> 3;                 // 4 outputs
    int hw0  = rowt * WW;
    int obase = oh * 128;

    float acc[4][4];
    #pragma unroll
    for (int j = 0; j < 4; j++)
        #pragma unroll
        for (int i = 0; i < 4; i++) acc[j][i] = 0.f;

    for (int c0 = 0; c0 < C; c0 += KC) {
        // stage feat tile [ch][px]
        {
            int px = tid & 31, cq = tid >> 5;   // cq 0..7
            int c = cq * 4;
            size_t pixi = (size_t)b * HWSZ + hw0 + px;
            const float* fp = (c0 < CV) ? &qv[pixi * CV + c0 + c]
                                        : &mo[pixi * CV + (c0 - CV) + c];
            float4 v = *(const float4*)fp;
            inT[c + 0][px] = v.x; inT[c + 1][px] = v.y;
            inT[c + 2][px] = v.z; inT[c + 3][px] = v.w;
        }
        // stage weight tile transposed [ch][o]
        #pragma unroll
        for (int j = 0; j < 4; j++) {
            int f  = tid + j * 256;      // float4 idx 0..1023
            int o  = f >> 3;             // 0..127
            int c4 = (f & 7) * 4;
            float4 v = *(const float4*)&wsm[(size_t)(obase + o) * C + c0 + c4];
            wTt[c4 + 0][o] = v.x; wTt[c4 + 1][o] = v.y;
            wTt[c4 + 2][o] = v.z; wTt[c4 + 3][o] = v.w;
        }
        __syncthreads();

        #pragma unroll 8
        for (int k = 0; k < KC; k++) {
            float4 iv  = *(const float4*)&inT[k][tx * 4];
            float4 wv4 = *(const float4*)&wTt[k][ty * 4];
            acc[0][0] += wv4.x * iv.x; acc[0][1] += wv4.x * iv.y;
            acc[0][2] += wv4.x * iv.z; acc[0][3] += wv4.x * iv.w;
            acc[1][0] += wv4.y * iv.x; acc[1][1] += wv4.y * iv.y;
            acc[1][2] += wv4.y * iv.z; acc[1][3] += wv4.y * iv.w;
            acc[2][0] += wv4.z * iv.x; acc[2][1] += wv4.z * iv.y;
            acc[2][2] += wv4.z * iv.z; acc[2][3] += wv4.z * iv.w;
            acc[3][0] += wv4.w * iv.x; acc[3][1] += wv4.w * iv.y;
            acc[3][2] += wv4.w * iv.z; acc[3][3] += wv4.w * iv.w;
        }
        __syncthreads();
    }

    #pragma unroll
    for (int j = 0; j < 4; j++) {
        int o = obase + ty * 4 + j;
        float inv = g[o] * rsqrtf(var[o] + 1e-5f);
        float sh  = bta[o] - mean[o] * inv;
        float4 r;
        r.x = fmaxf(acc[j][0] * inv + sh, 0.f);
        r.y = fmaxf(acc[j][1] * inv + sh, 0.f);
        r.z = fmaxf(acc[j][2] * inv + sh, 0.f);
        r.w = fmaxf(acc[j][3] * inv + sh, 0.f);
        *(float4*)&out[((size_t)(b * C + o)) * HWSZ + hw0 + tx * 4] = r;
    }
}

extern "C" void kernel_launch(void* const* d_in, const int* in_sizes, int n_in,
                              void* d_out, int out_size, void* d_ws, size_t ws_size,
                              hipStream_t stream) {
    const float* x    = (const float*)d_in[0];
    const float* mem  = (const float*)d_in[1];
    const float* w_qk = (const float*)d_in[2];
    const float* w_qv = (const float*)d_in[3];
    const float* w_mk = (const float*)d_in[4];
    const float* w_mv = (const float*)d_in[5];
    const float* wsm  = (const float*)d_in[6];
    const float* g    = (const float*)d_in[7];
    const float* bta  = (const float*)d_in[8];
    const float* mean = (const float*)d_in[9];
    const float* var  = (const float*)d_in[10];
    float* out = (float*)d_out;
    float* ws  = (float*)d_ws;

    {
        int n = (int)ZERO_N;
        k_zero<<<(n + 255) / 256, 256, 0, stream>>>(ws + OFF_MK, n);
    }
    k_proj<<<8 * 32, 256, 0, stream>>>(x, mem, w_qk, w_qv, w_mk, w_mv, ws);
    k_attn<<<B * HWSZ, 256, 0, stream>>>(ws + OFF_QK, ws + OFF_MK, ws + OFF_ATTN);
    {
        int n = B * HH * KK;
        k_softmax<<<(n + 255) / 256, 256, 0, stream>>>(ws + OFF_ATTN);
    }
    k_av<<<B * HWSZ, 128, 0, stream>>>(ws + OFF_ATTN, ws + OFF_MV, ws + OFF_MO);
    k_out<<<B * 32 * 2, 256, 0, stream>>>(ws + OFF_QV, ws + OFF_MO, wsm, g, bta, mean, var, out);
}